// Round 3
// baseline (130.097 us; speedup 1.0000x reference)
//
#include <hip/hip_runtime.h>
#include <hip/hip_bf16.h>

#define B_ 8
#define N_ 512

typedef __attribute__((ext_vector_type(8))) __bf16 bf16x8;
typedef __attribute__((ext_vector_type(8))) _Float16 f16x8;
typedef __attribute__((ext_vector_type(4))) _Float16 f16x4;
typedef __attribute__((ext_vector_type(2))) _Float16 h2;
typedef __attribute__((ext_vector_type(4))) float f32x4;
typedef __attribute__((ext_vector_type(4))) unsigned int u32x4;
typedef __attribute__((ext_vector_type(2))) unsigned int u32x2;

// pack two fp32 into bf16x2 by truncation: 1 v_perm_b32
__device__ __forceinline__ unsigned pk_bf16(float hi, float lo) {
    return __builtin_amdgcn_perm(__builtin_bit_cast(unsigned, hi),
                                 __builtin_bit_cast(unsigned, lo), 0x07060302u);
}

__device__ __forceinline__ h2 pkrtz(float a, float b) {
    return __builtin_bit_cast(h2, __builtin_amdgcn_cvt_pkrtz(a, b));
}
__device__ __forceinline__ unsigned pkrtz_u(float a, float b) {
    return __builtin_bit_cast(unsigned, __builtin_amdgcn_cvt_pkrtz(a, b));
}
// relu (pk_max_f16 vs 0) on a packed pair, returned as dword
__device__ __forceinline__ unsigned relu2_u(h2 v) {
    const h2 z2 = {(_Float16)0.0f, (_Float16)0.0f};
    return __builtin_bit_cast(unsigned, __builtin_elementwise_max(v, z2));
}

// ---------------- mega kernel: adj (dual-chain MFMA) | node MLP | prep | zero
// [0,1024)     adjacency MLP: block = (batch, i-group of 8, j-half of 256).
//              Each wave owns TWO i-rows -> two independent L0->L1->L2 MFMA
//              chains per j-tile (latency hiding), bj prefetched 1 tile ahead,
//              dual-row merged store (lanes 0-15 row A, 16-31 row B).
// [1024,2048)  node MLP, 4 rows/block
// [2048,2304)  w0t transpose (coalesced reads)
// [2304,2432)  w1t transpose
// [2432,2436)  zero d_out
__global__ __launch_bounds__(256) void k_mega(
    const float* __restrict__ coords,
    const float* __restrict__ fw0, const float* __restrict__ fb0,
    const float* __restrict__ fw1, const float* __restrict__ fb1,
    const float* __restrict__ aw0, const float* __restrict__ ab0,
    const float* __restrict__ aw1, const float* __restrict__ ab1,
    const float* __restrict__ aw2, const float* __restrict__ ab2,
    const float* __restrict__ uw0, const float* __restrict__ uw1,
    __bf16* __restrict__ h_bf, __bf16* __restrict__ h_t,
    __bf16* __restrict__ w0t, __bf16* __restrict__ w1t,
    __bf16* __restrict__ A,
    float* __restrict__ out, int out_size)
{
    const int blk = blockIdx.x;
    const int t = threadIdx.x;

    if (blk < 1024) {
        // ================= adjacency MLP =================
        __shared__ __align__(16) _Float16 s_aw1p[4096];
        __shared__ __align__(16) float s_w[576];   // aw0|ab0|aw2|ab1
        __shared__ __align__(8) unsigned s_cj[256][2];

        const int b = blk >> 7;
        const int rest = blk & 127;
        const int jh = rest & 1;          // j-half
        const int ig = rest >> 1;         // i-group (8 rows)

        // ---- prologue: all-coalesced staging ----
        {
            // aw1: coalesced read (thread owns 16 consecutive floats = one
            // row-segment), f16 scatter-store into fragment layout.
            f32x4 wv[4];
#pragma unroll
            for (int p = 0; p < 4; ++p)
                wv[p] = *(const f32x4*)(aw1 + t * 16 + p * 4);
            const int row = t >> 2;
            const int ct = t & 3;
            const int s = row >> 5;
            const int qq = (row >> 3) & 3;
            const int j = row & 7;
            const int base = s * 2048 + ct * 512 + qq * 128 + j;
#pragma unroll
            for (int e = 0; e < 16; ++e)
                s_aw1p[base + e * 8] = (_Float16)wv[e >> 2][e & 3];

            // aw0(384) | ab0(64) | aw2(64) | ab1(64) -> s_w[0..576)
            if (t < 144) {
                const int o = t * 4;
                f32x4 v;
                if (o < 384)      v = *(const f32x4*)(aw0 + o);
                else if (o < 448) v = *(const f32x4*)(ab0 + (o - 384));
                else if (o < 512) v = *(const f32x4*)(aw2 + (o - 448));
                else              v = *(const f32x4*)(ab1 + (o - 512));
                *(f32x4*)&s_w[o] = v;
            }

            // cj for this block's 256-j half, packed f16 {c0,c1,c2,1}
            const float* cj = coords + (size_t)(b * N_ + jh * 256 + t) * 3;
            s_cj[t][0] = pkrtz_u(cj[0], cj[1]);
            s_cj[t][1] = pkrtz_u(cj[2], 1.0f);
        }
        __syncthreads();

        const int l = t & 63;
        const int wave = t >> 6;
        const int q = l >> 4;
        const int m = l & 15;
        const int i0 = ig * 8 + wave * 2;      // rows i0, i0+1

        const float* cp = coords + (size_t)(b * N_ + i0) * 3;
        const float cA0 = cp[0], cA1 = cp[1], cA2 = cp[2];
        const float cB0 = cp[3], cB1 = cp[4], cB2 = cp[5];

        // ---- layer-0 A-fragments for BOTH rows ----
        // MFMA t4 row m -> ch = (m>>2)*8 + (m&3) + {0,4,32,36}[t4].
        f16x4 a0fA[4], a0fB[4];
        {
            const int chb = ((m >> 2) << 3) + (m & 3);
            const int offs[4] = {0, 4, 32, 36};
#pragma unroll
            for (int t4 = 0; t4 < 4; ++t4) {
                const int ch = chb + offs[t4];
                float w3 = s_w[192 + ch], w4 = s_w[256 + ch], w5 = s_w[320 + ch];
                float w0v = s_w[ch], w1v = s_w[64 + ch], w2v = s_w[128 + ch];
                float bch = s_w[384 + ch];
                float oA = bch + cA0 * w0v + cA1 * w1v + cA2 * w2v;
                float oB = bch + cB0 * w0v + cB1 * w1v + cB2 * w2v;
                unsigned w34 = (q == 0) ? pkrtz_u(w3, w4) : 0u;
                u32x2 fa, fb;
                fa[0] = w34;
                fa[1] = (q == 0) ? pkrtz_u(w5, oA) : 0u;
                fb[0] = w34;
                fb[1] = (q == 0) ? pkrtz_u(w5, oB) : 0u;
                a0fA[t4] = __builtin_bit_cast(f16x4, fa);
                a0fB[t4] = __builtin_bit_cast(f16x4, fb);
            }
        }

        // ---- layer-2 reduction A-fragments (aw2 from LDS) ----
        f16x4 ewf[4];
#pragma unroll
        for (int ct = 0; ct < 4; ++ct) {
            const float* ep = &s_w[448 + ct * 16 + (q << 2)];
            u32x2 fr;
            fr[0] = pkrtz_u(ep[0], ep[1]);
            fr[1] = pkrtz_u(ep[2], ep[3]);
            ewf[ct] = __builtin_bit_cast(f16x4, fr);
        }

        f16x8 bfr[2][4];
#pragma unroll
        for (int s = 0; s < 2; ++s)
#pragma unroll
            for (int ct = 0; ct < 4; ++ct)
                bfr[s][ct] = *(const f16x8*)&s_aw1p[s * 2048 + ct * 512 + q * 128 + m * 8];

        f32x4 ab1q[4];
#pragma unroll
        for (int ct = 0; ct < 4; ++ct)
            ab1q[ct] = *(const f32x4*)&s_w[512 + ct * 16 + (q << 2)];

        const float ab2s = ab2[0];
        const f32x4 pr0 = {ab2s, ab2s, ab2s, ab2s};
        const f32x4 zf = {0.f, 0.f, 0.f, 0.f};

        // dual-row store base: lanes 0-15 -> row i0, lanes 16-31 -> row i0+1
        __bf16* ArowP = A + ((size_t)(b * N_ + i0) << 9) + jh * 256;
        const int idx0 = ((l >> 4) << 9) + (l & 15);   // valid for l<32

        u32x2 bjw = *(const u32x2*)s_cj[m];

#pragma unroll 1
        for (int tt = 0; tt < 16; ++tt) {
            u32x2 bjn = *(const u32x2*)s_cj[(((tt + 1) & 15) << 4) + m];
            f16x4 bj = __builtin_bit_cast(f16x4, bjw);

            // layer 0: 4 row-permuted MFMAs per chain (K=16, k=0..3 live)
            f32x4 dA0 = __builtin_amdgcn_mfma_f32_16x16x16f16(a0fA[0], bj, zf, 0, 0, 0);
            f32x4 dA1 = __builtin_amdgcn_mfma_f32_16x16x16f16(a0fA[1], bj, zf, 0, 0, 0);
            f32x4 dA2 = __builtin_amdgcn_mfma_f32_16x16x16f16(a0fA[2], bj, zf, 0, 0, 0);
            f32x4 dA3 = __builtin_amdgcn_mfma_f32_16x16x16f16(a0fA[3], bj, zf, 0, 0, 0);
            f32x4 dB0 = __builtin_amdgcn_mfma_f32_16x16x16f16(a0fB[0], bj, zf, 0, 0, 0);
            f32x4 dB1 = __builtin_amdgcn_mfma_f32_16x16x16f16(a0fB[1], bj, zf, 0, 0, 0);
            f32x4 dB2 = __builtin_amdgcn_mfma_f32_16x16x16f16(a0fB[2], bj, zf, 0, 0, 0);
            f32x4 dB3 = __builtin_amdgcn_mfma_f32_16x16x16f16(a0fB[3], bj, zf, 0, 0, 0);

            // relu + pack straight into layer-1 B-fragments (both chains)
            u32x4 paA, pbA, paB, pbB;
            paA[0] = relu2_u(pkrtz(dA0[0], dA0[1]));
            paA[1] = relu2_u(pkrtz(dA0[2], dA0[3]));
            paA[2] = relu2_u(pkrtz(dA1[0], dA1[1]));
            paA[3] = relu2_u(pkrtz(dA1[2], dA1[3]));
            pbA[0] = relu2_u(pkrtz(dA2[0], dA2[1]));
            pbA[1] = relu2_u(pkrtz(dA2[2], dA2[3]));
            pbA[2] = relu2_u(pkrtz(dA3[0], dA3[1]));
            pbA[3] = relu2_u(pkrtz(dA3[2], dA3[3]));
            paB[0] = relu2_u(pkrtz(dB0[0], dB0[1]));
            paB[1] = relu2_u(pkrtz(dB0[2], dB0[3]));
            paB[2] = relu2_u(pkrtz(dB1[0], dB1[1]));
            paB[3] = relu2_u(pkrtz(dB1[2], dB1[3]));
            pbB[0] = relu2_u(pkrtz(dB2[0], dB2[1]));
            pbB[1] = relu2_u(pkrtz(dB2[2], dB2[3]));
            pbB[2] = relu2_u(pkrtz(dB3[0], dB3[1]));
            pbB[3] = relu2_u(pkrtz(dB3[2], dB3[3]));
            f16x8 a0A = __builtin_bit_cast(f16x8, paA);
            f16x8 a1A = __builtin_bit_cast(f16x8, pbA);
            f16x8 a0B = __builtin_bit_cast(f16x8, paB);
            f16x8 a1B = __builtin_bit_cast(f16x8, pbB);

            // layer 1 transposed MFMA (f16); ab1 folded into C; two chains
            f32x4 cA0v = __builtin_amdgcn_mfma_f32_16x16x32_f16(bfr[0][0], a0A, ab1q[0], 0, 0, 0);
            cA0v = __builtin_amdgcn_mfma_f32_16x16x32_f16(bfr[1][0], a1A, cA0v, 0, 0, 0);
            f32x4 cA1v = __builtin_amdgcn_mfma_f32_16x16x32_f16(bfr[0][1], a0A, ab1q[1], 0, 0, 0);
            cA1v = __builtin_amdgcn_mfma_f32_16x16x32_f16(bfr[1][1], a1A, cA1v, 0, 0, 0);
            f32x4 cA2v = __builtin_amdgcn_mfma_f32_16x16x32_f16(bfr[0][2], a0A, ab1q[2], 0, 0, 0);
            cA2v = __builtin_amdgcn_mfma_f32_16x16x32_f16(bfr[1][2], a1A, cA2v, 0, 0, 0);
            f32x4 cA3v = __builtin_amdgcn_mfma_f32_16x16x32_f16(bfr[0][3], a0A, ab1q[3], 0, 0, 0);
            cA3v = __builtin_amdgcn_mfma_f32_16x16x32_f16(bfr[1][3], a1A, cA3v, 0, 0, 0);
            f32x4 cB0v = __builtin_amdgcn_mfma_f32_16x16x32_f16(bfr[0][0], a0B, ab1q[0], 0, 0, 0);
            cB0v = __builtin_amdgcn_mfma_f32_16x16x32_f16(bfr[1][0], a1B, cB0v, 0, 0, 0);
            f32x4 cB1v = __builtin_amdgcn_mfma_f32_16x16x32_f16(bfr[0][1], a0B, ab1q[1], 0, 0, 0);
            cB1v = __builtin_amdgcn_mfma_f32_16x16x32_f16(bfr[1][1], a1B, cB1v, 0, 0, 0);
            f32x4 cB2v = __builtin_amdgcn_mfma_f32_16x16x32_f16(bfr[0][2], a0B, ab1q[2], 0, 0, 0);
            cB2v = __builtin_amdgcn_mfma_f32_16x16x32_f16(bfr[1][2], a1B, cB2v, 0, 0, 0);
            f32x4 cB3v = __builtin_amdgcn_mfma_f32_16x16x32_f16(bfr[0][3], a0B, ab1q[3], 0, 0, 0);
            cB3v = __builtin_amdgcn_mfma_f32_16x16x32_f16(bfr[1][3], a1B, cB3v, 0, 0, 0);

            // layer 2: relu + pack, reduce via 2 independent 2-chain MFMAs/chain
            u32x2 rA0, rA1, rA2, rA3, rB0, rB1, rB2, rB3;
            rA0[0] = relu2_u(pkrtz(cA0v[0], cA0v[1]));
            rA0[1] = relu2_u(pkrtz(cA0v[2], cA0v[3]));
            rA1[0] = relu2_u(pkrtz(cA1v[0], cA1v[1]));
            rA1[1] = relu2_u(pkrtz(cA1v[2], cA1v[3]));
            rA2[0] = relu2_u(pkrtz(cA2v[0], cA2v[1]));
            rA2[1] = relu2_u(pkrtz(cA2v[2], cA2v[3]));
            rA3[0] = relu2_u(pkrtz(cA3v[0], cA3v[1]));
            rA3[1] = relu2_u(pkrtz(cA3v[2], cA3v[3]));
            rB0[0] = relu2_u(pkrtz(cB0v[0], cB0v[1]));
            rB0[1] = relu2_u(pkrtz(cB0v[2], cB0v[3]));
            rB1[0] = relu2_u(pkrtz(cB1v[0], cB1v[1]));
            rB1[1] = relu2_u(pkrtz(cB1v[2], cB1v[3]));
            rB2[0] = relu2_u(pkrtz(cB2v[0], cB2v[1]));
            rB2[1] = relu2_u(pkrtz(cB2v[2], cB2v[3]));
            rB3[0] = relu2_u(pkrtz(cB3v[0], cB3v[1]));
            rB3[1] = relu2_u(pkrtz(cB3v[2], cB3v[3]));

            f32x4 prAa = __builtin_amdgcn_mfma_f32_16x16x16f16(
                ewf[0], __builtin_bit_cast(f16x4, rA0), pr0, 0, 0, 0);
            prAa = __builtin_amdgcn_mfma_f32_16x16x16f16(
                ewf[1], __builtin_bit_cast(f16x4, rA1), prAa, 0, 0, 0);
            f32x4 prAb = __builtin_amdgcn_mfma_f32_16x16x16f16(
                ewf[2], __builtin_bit_cast(f16x4, rA2), zf, 0, 0, 0);
            prAb = __builtin_amdgcn_mfma_f32_16x16x16f16(
                ewf[3], __builtin_bit_cast(f16x4, rA3), prAb, 0, 0, 0);
            f32x4 prBa = __builtin_amdgcn_mfma_f32_16x16x16f16(
                ewf[0], __builtin_bit_cast(f16x4, rB0), pr0, 0, 0, 0);
            prBa = __builtin_amdgcn_mfma_f32_16x16x16f16(
                ewf[1], __builtin_bit_cast(f16x4, rB1), prBa, 0, 0, 0);
            f32x4 prBb = __builtin_amdgcn_mfma_f32_16x16x16f16(
                ewf[2], __builtin_bit_cast(f16x4, rB2), zf, 0, 0, 0);
            prBb = __builtin_amdgcn_mfma_f32_16x16x16f16(
                ewf[3], __builtin_bit_cast(f16x4, rB3), prBb, 0, 0, 0);

            // merged dual-row store: lanes 0-15 row A, lanes 16-31 row B
            float vA = prAa[0] + prAb[0];
            float vB = prBa[0] + prBb[0];
            float v = (l < 16) ? vA : vB;
            if (l < 32) ArowP[idx0 + (tt << 4)] = (__bf16)fmaxf(v, 0.0f);

            bjw = bjn;
        }
    } else if (blk < 2048) {
        // ================= node MLP: 4 rows/block =================
        const int row0 = (blk - 1024) << 2;
        const int b = row0 >> 9;
        const int n0 = row0 & 511;
        __shared__ float cds4[4][4];
        __shared__ float hid4[4][64];
        if (t < 12) {
            int r = t / 3, d = t - 3 * r;
            cds4[r][d] = coords[(size_t)row0 * 3 + t];
        }
        __syncthreads();
        {
            int r = t >> 6, ch = t & 63;
            float v = fb0[ch];
            v += cds4[r][0] * fw0[0 * 64 + ch];
            v += cds4[r][1] * fw0[1 * 64 + ch];
            v += cds4[r][2] * fw0[2 * 64 + ch];
            hid4[r][ch] = fmaxf(v, 0.0f);
        }
        __syncthreads();
        {
            int ch = t & 127;
            int rp = (t >> 7) << 1;          // rows rp, rp+1
            float hv0 = fb1[ch], hv1 = hv0;
#pragma unroll 4
            for (int k = 0; k < 64; ++k) {
                float w = fw1[k * 128 + ch];
                hv0 += hid4[rp][k] * w;
                hv1 += hid4[rp + 1][k] * w;
            }
            hv0 = fmaxf(hv0, 0.0f);
            hv1 = fmaxf(hv1, 0.0f);
            h_bf[((size_t)(row0 + rp) << 7) + ch] = (__bf16)hv0;
            h_bf[((size_t)(row0 + rp + 1) << 7) + ch] = (__bf16)hv1;
            *(unsigned*)(h_t + (size_t)(b * 128 + ch) * 512 + n0 + rp) =
                pk_bf16(hv1, hv0);
        }
    } else if (blk < 2304) {
        // ---- w0t[c][k] = uw0[perm(k)][c]; coalesced read ----
        int k = blk - 2048;
        int c = t;
        int src = (k < 128) ? k : (k + 3);
        w0t[(size_t)c * 256 + k] = (__bf16)uw0[(size_t)src * 256 + c];
    } else if (blk < 2432) {
        // ---- w1t[c][k] = uw1[k][c]; coalesced read ----
        int id = (blk - 2304) * 256 + t;
        int c = id & 127, k = id >> 7;
        w1t[(size_t)c * 256 + k] = (__bf16)uw1[(size_t)k * 128 + c];
    } else {
        int i = (blk - 2432) * 256 + t;
        if (i < out_size) out[i] = 0.0f;
    }
}

// ---------------- fused  V = A@h (MFMA, K-split x2)  +  update MLP ----------
// 256 blocks x 1024 thr (16 waves). act/u1 rows padded 256->264 bf16 to break
// the 512B-stride 16-way LDS bank conflict on A-fragment ds_read_b128.
__global__ __launch_bounds__(1024) void k_aggupd(
    const __bf16* __restrict__ A, const __bf16* __restrict__ h_t,
    const __bf16* __restrict__ h_bf, const float* __restrict__ coords,
    const float* __restrict__ uw0, const float* __restrict__ ub0,
    const __bf16* __restrict__ w0t, const __bf16* __restrict__ w1t,
    const float* __restrict__ ub1,
    float* __restrict__ out)
{
    const int t = threadIdx.x;
    const int w = t >> 6;            // wave 0..15
    const int gw = w & 7;            // n-tile
    const int ks = w >> 3;           // K-half
    const int l = t & 63;
    const int q = l >> 4;
    const int m = l & 15;
    const int row0 = blockIdx.x << 4;   // 16 GLOBAL rows, same b
    const int b = row0 >> 9;

    __shared__ __align__(16) __bf16 act[16][264];  // [row][k], k=[h|V], padded
    __shared__ __align__(16) __bf16 u1[16][264];
    __shared__ float vp[2][16][128];
    __shared__ float cds[16][4];

    // stage h part of act: 1024 thr x 4B covers 16x128 bf16
    {
        unsigned hv = *(const unsigned*)(h_bf + ((size_t)row0 << 7) + t * 2);
        *(unsigned*)&act[(t * 2) >> 7][(t * 2) & 127] = hv;
    }
    if (t < 48) {
        int r = t / 3, d = t - 3 * r;
        cds[r][d] = coords[(size_t)row0 * 3 + t];
    }

    // ---- aggregate: V n-tile gw, K-half ks (A indexed by global row) ----
    const __bf16* Ar = A + (size_t)(row0 + m) * 512 + ks * 256 + q * 8;
    const __bf16* hp = h_t + ((size_t)b << 16) + (size_t)(gw * 16 + m) * 512
                       + ks * 256 + q * 8;
    f32x4 acc = {0.f, 0.f, 0.f, 0.f};
#pragma unroll 4
    for (int kt = 0; kt < 8; ++kt) {
        bf16x8 av = *(const bf16x8*)(Ar + kt * 32);
        bf16x8 bv = *(const bf16x8*)(hp + kt * 32);
        acc = __builtin_amdgcn_mfma_f32_16x16x32_bf16(av, bv, acc, 0, 0, 0);
    }
#pragma unroll
    for (int r = 0; r < 4; ++r)
        vp[ks][q * 4 + r][gw * 16 + m] = acc[r];
    __syncthreads();

    // combine K-halves -> act V part (1024 thr x 2 values)
#pragma unroll
    for (int it = 0; it < 2; ++it) {
        int idx = t + it * 1024;
        int row = idx >> 7, ch = idx & 127;
        act[row][128 + ch] = (__bf16)(vp[0][row][ch] + vp[1][row][ch]);
    }
    __syncthreads();

    // ---- layer 1: col c = w*16 + m (16 waves cover 256 cols) ----
    bf16x8 af[8];
#pragma unroll
    for (int ch = 0; ch < 8; ++ch)
        af[ch] = *(const bf16x8*)&act[m][q * 8 + 32 * ch];
    {
        const int c = w * 16 + m;
        const float wx = uw0[128 * 256 + c];
        const float wy = uw0[129 * 256 + c];
        const float wz = uw0[130 * 256 + c];
        const float bias = ub0[c];
        f32x4 a1c;
#pragma unroll
        for (int r = 0; r < 4; ++r)
            a1c[r] = bias + cds[q * 4 + r][0] * wx + cds[q * 4 + r][1] * wy
                          + cds[q * 4 + r][2] * wz;
        const __bf16* wp = w0t + (size_t)c * 256 + q * 8;
#pragma unroll
        for (int ch = 0; ch < 8; ++ch) {
            bf16x8 bfr = *(const bf16x8*)(wp + 32 * ch);
            a1c = __builtin_amdgcn_mfma_f32_16x16x32_bf16(af[ch], bfr, a1c, 0, 0, 0);
        }
#pragma unroll
        for (int r = 0; r < 4; ++r)
            u1[q * 4 + r][c] = (__bf16)fmaxf(a1c[r], 0.0f);
    }
    __syncthreads();

    // ---- layer 2: cols w*16 + m on waves 0..7 ----
    if (w < 8) {
        bf16x8 af2[8];
#pragma unroll
        for (int ch = 0; ch < 8; ++ch)
            af2[ch] = *(const bf16x8*)&u1[m][q * 8 + 32 * ch];
        const int c = w * 16 + m;
        float bias = ub1[c];
        f32x4 a2c = {bias, bias, bias, bias};
        const __bf16* wp = w1t + (size_t)c * 256 + q * 8;
#pragma unroll
        for (int ch = 0; ch < 8; ++ch) {
            bf16x8 bfr = *(const bf16x8*)(wp + 32 * ch);
            a2c = __builtin_amdgcn_mfma_f32_16x16x32_bf16(af2[ch], bfr, a2c, 0, 0, 0);
        }
        float mx = fmaxf(fmaxf(a2c[0], a2c[1]), fmaxf(a2c[2], a2c[3]));
        mx = fmaxf(mx, 0.0f);
        mx = fmaxf(mx, __shfl_xor(mx, 16, 64));
        mx = fmaxf(mx, __shfl_xor(mx, 32, 64));
        if (l < 16)
            atomicMax((int*)(out + ((size_t)b << 7) + c), __float_as_int(mx));
    }
}

extern "C" void kernel_launch(void* const* d_in, const int* in_sizes, int n_in,
                              void* d_out, int out_size, void* d_ws, size_t ws_size,
                              hipStream_t stream)
{
    const float* coords = (const float*)d_in[0];
    const float* fw0 = (const float*)d_in[1];
    const float* fb0 = (const float*)d_in[2];
    const float* fw1 = (const float*)d_in[3];
    const float* fb1 = (const float*)d_in[4];
    const float* aw0 = (const float*)d_in[5];
    const float* ab0 = (const float*)d_in[6];
    const float* aw1 = (const float*)d_in[7];
    const float* ab1 = (const float*)d_in[8];
    const float* aw2 = (const float*)d_in[9];
    const float* ab2 = (const float*)d_in[10];
    const float* uw0 = (const float*)d_in[11];
    const float* ub0 = (const float*)d_in[12];
    const float* uw1 = (const float*)d_in[13];
    const float* ub1 = (const float*)d_in[14];
    float* out = (float*)d_out;

    // workspace layout
    char* ws = (char*)d_ws;
    __bf16* A    = (__bf16*)(ws);                            // 4 MB
    __bf16* h_t  = (__bf16*)(ws + (4u << 20));               // 1 MB
    __bf16* h_bf = (__bf16*)(ws + (5u << 20));               // 1 MB
    __bf16* w0t  = (__bf16*)(ws + (6u << 20));               // 128 KB
    __bf16* w1t  = (__bf16*)(ws + (6u << 20) + (128u << 10));// 64 KB

    k_mega<<<2436, 256, 0, stream>>>(coords, fw0, fb0, fw1, fb1,
                                     aw0, ab0, aw1, ab1, aw2, ab2, uw0, uw1,
                                     h_bf, h_t, w0t, w1t, A, out, out_size);
    k_aggupd<<<256, 1024, 0, stream>>>(A, h_t, h_bf, coords, uw0, ub0,
                                       w0t, w1t, ub1, out);
}

// Round 4
// 129.366 us; speedup vs baseline: 1.0057x; 1.0057x over previous
//
#include <hip/hip_runtime.h>
#include <hip/hip_bf16.h>

#define B_ 8
#define N_ 512

typedef __attribute__((ext_vector_type(8))) __bf16 bf16x8;
typedef __attribute__((ext_vector_type(8))) _Float16 f16x8;
typedef __attribute__((ext_vector_type(4))) _Float16 f16x4;
typedef __attribute__((ext_vector_type(2))) _Float16 h2;
typedef __attribute__((ext_vector_type(4))) float f32x4;
typedef __attribute__((ext_vector_type(4))) unsigned int u32x4;
typedef __attribute__((ext_vector_type(2))) unsigned int u32x2;

// pack two fp32 into bf16x2 by truncation: 1 v_perm_b32
__device__ __forceinline__ unsigned pk_bf16(float hi, float lo) {
    return __builtin_amdgcn_perm(__builtin_bit_cast(unsigned, hi),
                                 __builtin_bit_cast(unsigned, lo), 0x07060302u);
}

__device__ __forceinline__ h2 pkrtz(float a, float b) {
    return __builtin_bit_cast(h2, __builtin_amdgcn_cvt_pkrtz(a, b));
}
__device__ __forceinline__ unsigned pkrtz_u(float a, float b) {
    return __builtin_bit_cast(unsigned, __builtin_amdgcn_cvt_pkrtz(a, b));
}
// relu (pk_max_f16 vs 0) on a packed pair, returned as dword
__device__ __forceinline__ unsigned relu2_u(h2 v) {
    const h2 z2 = {(_Float16)0.0f, (_Float16)0.0f};
    return __builtin_bit_cast(unsigned, __builtin_elementwise_max(v, z2));
}

// ---------------- mega kernel: adj (all-native-x32 MFMA) | node MLP | prep
// [0,1024)     adjacency MLP: block = (batch, i-group of 8, j-half of 256).
//              Wave owns TWO i-rows. ALL MFMAs are native 16x16x32_f16:
//              L0 zero-padded x32, L1 x32, L2 reduction repacked into
//              2 x32 per row (was 4 legacy x16). No legacy K=16 shapes.
// [1024,2048)  node MLP, 4 rows/block
// [2048,2304)  w0t transpose (coalesced reads)
// [2304,2432)  w1t transpose
// [2432,2436)  zero d_out
__global__ __launch_bounds__(256) void k_mega(
    const float* __restrict__ coords,
    const float* __restrict__ fw0, const float* __restrict__ fb0,
    const float* __restrict__ fw1, const float* __restrict__ fb1,
    const float* __restrict__ aw0, const float* __restrict__ ab0,
    const float* __restrict__ aw1, const float* __restrict__ ab1,
    const float* __restrict__ aw2, const float* __restrict__ ab2,
    const float* __restrict__ uw0, const float* __restrict__ uw1,
    __bf16* __restrict__ h_bf, __bf16* __restrict__ h_t,
    __bf16* __restrict__ w0t, __bf16* __restrict__ w1t,
    __bf16* __restrict__ A,
    float* __restrict__ out, int out_size)
{
    const int blk = blockIdx.x;
    const int t = threadIdx.x;

    if (blk < 1024) {
        // ================= adjacency MLP =================
        __shared__ __align__(16) _Float16 s_aw1p[4096];
        __shared__ __align__(16) float s_w[576];   // aw0|ab0|aw2|ab1
        __shared__ __align__(8) unsigned s_cj[256][2];

        const int b = blk >> 7;
        const int rest = blk & 127;
        const int jh = rest & 1;          // j-half
        const int ig = rest >> 1;         // i-group (8 rows)

        // ---- prologue: all-coalesced staging ----
        {
            // aw1: coalesced read (thread owns 16 consecutive floats = one
            // row-segment), f16 scatter-store into fragment layout.
            f32x4 wv[4];
#pragma unroll
            for (int p = 0; p < 4; ++p)
                wv[p] = *(const f32x4*)(aw1 + t * 16 + p * 4);
            const int row = t >> 2;
            const int ct = t & 3;
            const int s = row >> 5;
            const int qq = (row >> 3) & 3;
            const int j = row & 7;
            const int base = s * 2048 + ct * 512 + qq * 128 + j;
#pragma unroll
            for (int e = 0; e < 16; ++e)
                s_aw1p[base + e * 8] = (_Float16)wv[e >> 2][e & 3];

            // aw0(384) | ab0(64) | aw2(64) | ab1(64) -> s_w[0..576)
            if (t < 144) {
                const int o = t * 4;
                f32x4 v;
                if (o < 384)      v = *(const f32x4*)(aw0 + o);
                else if (o < 448) v = *(const f32x4*)(ab0 + (o - 384));
                else if (o < 512) v = *(const f32x4*)(aw2 + (o - 448));
                else              v = *(const f32x4*)(ab1 + (o - 512));
                *(f32x4*)&s_w[o] = v;
            }

            // cj for this block's 256-j half, packed f16 {c0,c1,c2,1}
            const float* cj = coords + (size_t)(b * N_ + jh * 256 + t) * 3;
            s_cj[t][0] = pkrtz_u(cj[0], cj[1]);
            s_cj[t][1] = pkrtz_u(cj[2], 1.0f);
        }
        __syncthreads();

        const int l = t & 63;
        const int wave = t >> 6;
        const int q = l >> 4;
        const int m = l & 15;
        const int i0 = ig * 8 + wave * 2;      // rows i0, i0+1

        const float* cp = coords + (size_t)(b * N_ + i0) * 3;
        const float cA0 = cp[0], cA1 = cp[1], cA2 = cp[2];
        const float cB0 = cp[3], cB1 = cp[4], cB2 = cp[5];

        // ---- layer-0 A-fragments for BOTH rows, x32 shape (K=4 live) ----
        // MFMA t4 row m -> ch = (m>>2)*8 + (m&3) + {0,4,32,36}[t4].
        f16x8 a0fA[4], a0fB[4];
        {
            const int chb = ((m >> 2) << 3) + (m & 3);
            const int offs[4] = {0, 4, 32, 36};
#pragma unroll
            for (int t4 = 0; t4 < 4; ++t4) {
                const int ch = chb + offs[t4];
                float w3 = s_w[192 + ch], w4 = s_w[256 + ch], w5 = s_w[320 + ch];
                float w0v = s_w[ch], w1v = s_w[64 + ch], w2v = s_w[128 + ch];
                float bch = s_w[384 + ch];
                float oA = bch + cA0 * w0v + cA1 * w1v + cA2 * w2v;
                float oB = bch + cB0 * w0v + cB1 * w1v + cB2 * w2v;
                unsigned w34 = (q == 0) ? pkrtz_u(w3, w4) : 0u;
                u32x4 fa, fb;
                fa[0] = w34;
                fa[1] = (q == 0) ? pkrtz_u(w5, oA) : 0u;
                fa[2] = 0u; fa[3] = 0u;
                fb[0] = w34;
                fb[1] = (q == 0) ? pkrtz_u(w5, oB) : 0u;
                fb[2] = 0u; fb[3] = 0u;
                a0fA[t4] = __builtin_bit_cast(f16x8, fa);
                a0fB[t4] = __builtin_bit_cast(f16x8, fb);
            }
        }

        // ---- layer-2 reduction A-fragments, x32 shape (K=32 full) ----
        // group g covers chs g*32 + (e>>2)*16 + q*4 + (e&3), e=0..7
        f16x8 ewf[2];
#pragma unroll
        for (int g = 0; g < 2; ++g) {
            const float* e0 = &s_w[448 + g * 32 + (q << 2)];
            const float* e1 = e0 + 16;
            u32x4 fr;
            fr[0] = pkrtz_u(e0[0], e0[1]);
            fr[1] = pkrtz_u(e0[2], e0[3]);
            fr[2] = pkrtz_u(e1[0], e1[1]);
            fr[3] = pkrtz_u(e1[2], e1[3]);
            ewf[g] = __builtin_bit_cast(f16x8, fr);
        }

        f16x8 bfr[2][4];
#pragma unroll
        for (int s = 0; s < 2; ++s)
#pragma unroll
            for (int ct = 0; ct < 4; ++ct)
                bfr[s][ct] = *(const f16x8*)&s_aw1p[s * 2048 + ct * 512 + q * 128 + m * 8];

        f32x4 ab1q[4];
#pragma unroll
        for (int ct = 0; ct < 4; ++ct)
            ab1q[ct] = *(const f32x4*)&s_w[512 + ct * 16 + (q << 2)];

        const float ab2s = ab2[0];
        const f32x4 pr0 = {ab2s, ab2s, ab2s, ab2s};
        const f32x4 zf = {0.f, 0.f, 0.f, 0.f};

        // dual-row store base: lanes 0-15 -> row i0, lanes 16-31 -> row i0+1
        __bf16* ArowP = A + ((size_t)(b * N_ + i0) << 9) + jh * 256;
        const int idx0 = ((l >> 4) << 9) + (l & 15);   // valid for l<32

        u32x2 bjw = *(const u32x2*)s_cj[m];

#pragma unroll 1
        for (int tt = 0; tt < 16; ++tt) {
            u32x2 bjn = *(const u32x2*)s_cj[(((tt + 1) & 15) << 4) + m];
            u32x4 bj4;
            bj4[0] = bjw[0]; bj4[1] = bjw[1]; bj4[2] = 0u; bj4[3] = 0u;
            f16x8 bj = __builtin_bit_cast(f16x8, bj4);

            // layer 0: 4 row-permuted x32 MFMAs per chain (k=0..3 live)
            f32x4 dA0 = __builtin_amdgcn_mfma_f32_16x16x32_f16(a0fA[0], bj, zf, 0, 0, 0);
            f32x4 dA1 = __builtin_amdgcn_mfma_f32_16x16x32_f16(a0fA[1], bj, zf, 0, 0, 0);
            f32x4 dA2 = __builtin_amdgcn_mfma_f32_16x16x32_f16(a0fA[2], bj, zf, 0, 0, 0);
            f32x4 dA3 = __builtin_amdgcn_mfma_f32_16x16x32_f16(a0fA[3], bj, zf, 0, 0, 0);
            f32x4 dB0 = __builtin_amdgcn_mfma_f32_16x16x32_f16(a0fB[0], bj, zf, 0, 0, 0);
            f32x4 dB1 = __builtin_amdgcn_mfma_f32_16x16x32_f16(a0fB[1], bj, zf, 0, 0, 0);
            f32x4 dB2 = __builtin_amdgcn_mfma_f32_16x16x32_f16(a0fB[2], bj, zf, 0, 0, 0);
            f32x4 dB3 = __builtin_amdgcn_mfma_f32_16x16x32_f16(a0fB[3], bj, zf, 0, 0, 0);

            // relu + pack straight into layer-1 B-fragments (both chains)
            u32x4 paA, pbA, paB, pbB;
            paA[0] = relu2_u(pkrtz(dA0[0], dA0[1]));
            paA[1] = relu2_u(pkrtz(dA0[2], dA0[3]));
            paA[2] = relu2_u(pkrtz(dA1[0], dA1[1]));
            paA[3] = relu2_u(pkrtz(dA1[2], dA1[3]));
            pbA[0] = relu2_u(pkrtz(dA2[0], dA2[1]));
            pbA[1] = relu2_u(pkrtz(dA2[2], dA2[3]));
            pbA[2] = relu2_u(pkrtz(dA3[0], dA3[1]));
            pbA[3] = relu2_u(pkrtz(dA3[2], dA3[3]));
            paB[0] = relu2_u(pkrtz(dB0[0], dB0[1]));
            paB[1] = relu2_u(pkrtz(dB0[2], dB0[3]));
            paB[2] = relu2_u(pkrtz(dB1[0], dB1[1]));
            paB[3] = relu2_u(pkrtz(dB1[2], dB1[3]));
            pbB[0] = relu2_u(pkrtz(dB2[0], dB2[1]));
            pbB[1] = relu2_u(pkrtz(dB2[2], dB2[3]));
            pbB[2] = relu2_u(pkrtz(dB3[0], dB3[1]));
            pbB[3] = relu2_u(pkrtz(dB3[2], dB3[3]));
            f16x8 a0A = __builtin_bit_cast(f16x8, paA);
            f16x8 a1A = __builtin_bit_cast(f16x8, pbA);
            f16x8 a0B = __builtin_bit_cast(f16x8, paB);
            f16x8 a1B = __builtin_bit_cast(f16x8, pbB);

            // layer 1 transposed MFMA (f16); ab1 folded into C; two chains
            f32x4 cA0v = __builtin_amdgcn_mfma_f32_16x16x32_f16(bfr[0][0], a0A, ab1q[0], 0, 0, 0);
            cA0v = __builtin_amdgcn_mfma_f32_16x16x32_f16(bfr[1][0], a1A, cA0v, 0, 0, 0);
            f32x4 cA1v = __builtin_amdgcn_mfma_f32_16x16x32_f16(bfr[0][1], a0A, ab1q[1], 0, 0, 0);
            cA1v = __builtin_amdgcn_mfma_f32_16x16x32_f16(bfr[1][1], a1A, cA1v, 0, 0, 0);
            f32x4 cA2v = __builtin_amdgcn_mfma_f32_16x16x32_f16(bfr[0][2], a0A, ab1q[2], 0, 0, 0);
            cA2v = __builtin_amdgcn_mfma_f32_16x16x32_f16(bfr[1][2], a1A, cA2v, 0, 0, 0);
            f32x4 cA3v = __builtin_amdgcn_mfma_f32_16x16x32_f16(bfr[0][3], a0A, ab1q[3], 0, 0, 0);
            cA3v = __builtin_amdgcn_mfma_f32_16x16x32_f16(bfr[1][3], a1A, cA3v, 0, 0, 0);
            f32x4 cB0v = __builtin_amdgcn_mfma_f32_16x16x32_f16(bfr[0][0], a0B, ab1q[0], 0, 0, 0);
            cB0v = __builtin_amdgcn_mfma_f32_16x16x32_f16(bfr[1][0], a1B, cB0v, 0, 0, 0);
            f32x4 cB1v = __builtin_amdgcn_mfma_f32_16x16x32_f16(bfr[0][1], a0B, ab1q[1], 0, 0, 0);
            cB1v = __builtin_amdgcn_mfma_f32_16x16x32_f16(bfr[1][1], a1B, cB1v, 0, 0, 0);
            f32x4 cB2v = __builtin_amdgcn_mfma_f32_16x16x32_f16(bfr[0][2], a0B, ab1q[2], 0, 0, 0);
            cB2v = __builtin_amdgcn_mfma_f32_16x16x32_f16(bfr[1][2], a1B, cB2v, 0, 0, 0);
            f32x4 cB3v = __builtin_amdgcn_mfma_f32_16x16x32_f16(bfr[0][3], a0B, ab1q[3], 0, 0, 0);
            cB3v = __builtin_amdgcn_mfma_f32_16x16x32_f16(bfr[1][3], a1B, cB3v, 0, 0, 0);

            // layer 2: relu + pack, then K=32 repack -> 2 x32 MFMAs per row
            u32x4 BA0, BA1, BB0, BB1;
            BA0[0] = relu2_u(pkrtz(cA0v[0], cA0v[1]));
            BA0[1] = relu2_u(pkrtz(cA0v[2], cA0v[3]));
            BA0[2] = relu2_u(pkrtz(cA1v[0], cA1v[1]));
            BA0[3] = relu2_u(pkrtz(cA1v[2], cA1v[3]));
            BA1[0] = relu2_u(pkrtz(cA2v[0], cA2v[1]));
            BA1[1] = relu2_u(pkrtz(cA2v[2], cA2v[3]));
            BA1[2] = relu2_u(pkrtz(cA3v[0], cA3v[1]));
            BA1[3] = relu2_u(pkrtz(cA3v[2], cA3v[3]));
            BB0[0] = relu2_u(pkrtz(cB0v[0], cB0v[1]));
            BB0[1] = relu2_u(pkrtz(cB0v[2], cB0v[3]));
            BB0[2] = relu2_u(pkrtz(cB1v[0], cB1v[1]));
            BB0[3] = relu2_u(pkrtz(cB1v[2], cB1v[3]));
            BB1[0] = relu2_u(pkrtz(cB2v[0], cB2v[1]));
            BB1[1] = relu2_u(pkrtz(cB2v[2], cB2v[3]));
            BB1[2] = relu2_u(pkrtz(cB3v[0], cB3v[1]));
            BB1[3] = relu2_u(pkrtz(cB3v[2], cB3v[3]));

            f32x4 prA = __builtin_amdgcn_mfma_f32_16x16x32_f16(
                ewf[0], __builtin_bit_cast(f16x8, BA0), pr0, 0, 0, 0);
            prA = __builtin_amdgcn_mfma_f32_16x16x32_f16(
                ewf[1], __builtin_bit_cast(f16x8, BA1), prA, 0, 0, 0);
            f32x4 prB = __builtin_amdgcn_mfma_f32_16x16x32_f16(
                ewf[0], __builtin_bit_cast(f16x8, BB0), pr0, 0, 0, 0);
            prB = __builtin_amdgcn_mfma_f32_16x16x32_f16(
                ewf[1], __builtin_bit_cast(f16x8, BB1), prB, 0, 0, 0);

            // merged dual-row store: lanes 0-15 row A, lanes 16-31 row B
            float v = (l < 16) ? prA[0] : prB[0];
            if (l < 32) ArowP[idx0 + (tt << 4)] = (__bf16)fmaxf(v, 0.0f);

            bjw = bjn;
        }
    } else if (blk < 2048) {
        // ================= node MLP: 4 rows/block =================
        const int row0 = (blk - 1024) << 2;
        const int b = row0 >> 9;
        const int n0 = row0 & 511;
        __shared__ float cds4[4][4];
        __shared__ float hid4[4][64];
        if (t < 12) {
            int r = t / 3, d = t - 3 * r;
            cds4[r][d] = coords[(size_t)row0 * 3 + t];
        }
        __syncthreads();
        {
            int r = t >> 6, ch = t & 63;
            float v = fb0[ch];
            v += cds4[r][0] * fw0[0 * 64 + ch];
            v += cds4[r][1] * fw0[1 * 64 + ch];
            v += cds4[r][2] * fw0[2 * 64 + ch];
            hid4[r][ch] = fmaxf(v, 0.0f);
        }
        __syncthreads();
        {
            int ch = t & 127;
            int rp = (t >> 7) << 1;          // rows rp, rp+1
            float hv0 = fb1[ch], hv1 = hv0;
#pragma unroll 4
            for (int k = 0; k < 64; ++k) {
                float w = fw1[k * 128 + ch];
                hv0 += hid4[rp][k] * w;
                hv1 += hid4[rp + 1][k] * w;
            }
            hv0 = fmaxf(hv0, 0.0f);
            hv1 = fmaxf(hv1, 0.0f);
            h_bf[((size_t)(row0 + rp) << 7) + ch] = (__bf16)hv0;
            h_bf[((size_t)(row0 + rp + 1) << 7) + ch] = (__bf16)hv1;
            *(unsigned*)(h_t + (size_t)(b * 128 + ch) * 512 + n0 + rp) =
                pk_bf16(hv1, hv0);
        }
    } else if (blk < 2304) {
        // ---- w0t[c][k] = uw0[perm(k)][c]; coalesced read ----
        int k = blk - 2048;
        int c = t;
        int src = (k < 128) ? k : (k + 3);
        w0t[(size_t)c * 256 + k] = (__bf16)uw0[(size_t)src * 256 + c];
    } else if (blk < 2432) {
        // ---- w1t[c][k] = uw1[k][c]; coalesced read ----
        int id = (blk - 2304) * 256 + t;
        int c = id & 127, k = id >> 7;
        w1t[(size_t)c * 256 + k] = (__bf16)uw1[(size_t)k * 128 + c];
    } else {
        int i = (blk - 2432) * 256 + t;
        if (i < out_size) out[i] = 0.0f;
    }
}

// ---------------- fused  V = A@h (MFMA, K-split x2)  +  update MLP ----------
// 256 blocks x 1024 thr (16 waves). act/u1 rows padded 256->264 bf16 to break
// the 512B-stride 16-way LDS bank conflict on A-fragment ds_read_b128.
__global__ __launch_bounds__(1024) void k_aggupd(
    const __bf16* __restrict__ A, const __bf16* __restrict__ h_t,
    const __bf16* __restrict__ h_bf, const float* __restrict__ coords,
    const float* __restrict__ uw0, const float* __restrict__ ub0,
    const __bf16* __restrict__ w0t, const __bf16* __restrict__ w1t,
    const float* __restrict__ ub1,
    float* __restrict__ out)
{
    const int t = threadIdx.x;
    const int w = t >> 6;            // wave 0..15
    const int gw = w & 7;            // n-tile
    const int ks = w >> 3;           // K-half
    const int l = t & 63;
    const int q = l >> 4;
    const int m = l & 15;
    const int row0 = blockIdx.x << 4;   // 16 GLOBAL rows, same b
    const int b = row0 >> 9;

    __shared__ __align__(16) __bf16 act[16][264];  // [row][k], k=[h|V], padded
    __shared__ __align__(16) __bf16 u1[16][264];
    __shared__ float vp[2][16][128];
    __shared__ float cds[16][4];

    // stage h part of act: 1024 thr x 4B covers 16x128 bf16
    {
        unsigned hv = *(const unsigned*)(h_bf + ((size_t)row0 << 7) + t * 2);
        *(unsigned*)&act[(t * 2) >> 7][(t * 2) & 127] = hv;
    }
    if (t < 48) {
        int r = t / 3, d = t - 3 * r;
        cds[r][d] = coords[(size_t)row0 * 3 + t];
    }

    // ---- aggregate: V n-tile gw, K-half ks (A indexed by global row) ----
    const __bf16* Ar = A + (size_t)(row0 + m) * 512 + ks * 256 + q * 8;
    const __bf16* hp = h_t + ((size_t)b << 16) + (size_t)(gw * 16 + m) * 512
                       + ks * 256 + q * 8;
    f32x4 acc = {0.f, 0.f, 0.f, 0.f};
#pragma unroll 4
    for (int kt = 0; kt < 8; ++kt) {
        bf16x8 av = *(const bf16x8*)(Ar + kt * 32);
        bf16x8 bv = *(const bf16x8*)(hp + kt * 32);
        acc = __builtin_amdgcn_mfma_f32_16x16x32_bf16(av, bv, acc, 0, 0, 0);
    }
#pragma unroll
    for (int r = 0; r < 4; ++r)
        vp[ks][q * 4 + r][gw * 16 + m] = acc[r];
    __syncthreads();

    // combine K-halves -> act V part (1024 thr x 2 values)
#pragma unroll
    for (int it = 0; it < 2; ++it) {
        int idx = t + it * 1024;
        int row = idx >> 7, ch = idx & 127;
        act[row][128 + ch] = (__bf16)(vp[0][row][ch] + vp[1][row][ch]);
    }
    __syncthreads();

    // ---- layer 1: col c = w*16 + m (16 waves cover 256 cols) ----
    bf16x8 af[8];
#pragma unroll
    for (int ch = 0; ch < 8; ++ch)
        af[ch] = *(const bf16x8*)&act[m][q * 8 + 32 * ch];
    {
        const int c = w * 16 + m;
        const float wx = uw0[128 * 256 + c];
        const float wy = uw0[129 * 256 + c];
        const float wz = uw0[130 * 256 + c];
        const float bias = ub0[c];
        f32x4 a1c;
#pragma unroll
        for (int r = 0; r < 4; ++r)
            a1c[r] = bias + cds[q * 4 + r][0] * wx + cds[q * 4 + r][1] * wy
                          + cds[q * 4 + r][2] * wz;
        const __bf16* wp = w0t + (size_t)c * 256 + q * 8;
#pragma unroll
        for (int ch = 0; ch < 8; ++ch) {
            bf16x8 bfr = *(const bf16x8*)(wp + 32 * ch);
            a1c = __builtin_amdgcn_mfma_f32_16x16x32_bf16(af[ch], bfr, a1c, 0, 0, 0);
        }
#pragma unroll
        for (int r = 0; r < 4; ++r)
            u1[q * 4 + r][c] = (__bf16)fmaxf(a1c[r], 0.0f);
    }
    __syncthreads();

    // ---- layer 2: cols w*16 + m on waves 0..7 ----
    if (w < 8) {
        bf16x8 af2[8];
#pragma unroll
        for (int ch = 0; ch < 8; ++ch)
            af2[ch] = *(const bf16x8*)&u1[m][q * 8 + 32 * ch];
        const int c = w * 16 + m;
        float bias = ub1[c];
        f32x4 a2c = {bias, bias, bias, bias};
        const __bf16* wp = w1t + (size_t)c * 256 + q * 8;
#pragma unroll
        for (int ch = 0; ch < 8; ++ch) {
            bf16x8 bfr = *(const bf16x8*)(wp + 32 * ch);
            a2c = __builtin_amdgcn_mfma_f32_16x16x32_bf16(af2[ch], bfr, a2c, 0, 0, 0);
        }
        float mx = fmaxf(fmaxf(a2c[0], a2c[1]), fmaxf(a2c[2], a2c[3]));
        mx = fmaxf(mx, 0.0f);
        mx = fmaxf(mx, __shfl_xor(mx, 16, 64));
        mx = fmaxf(mx, __shfl_xor(mx, 32, 64));
        if (l < 16)
            atomicMax((int*)(out + ((size_t)b << 7) + c), __float_as_int(mx));
    }
}

extern "C" void kernel_launch(void* const* d_in, const int* in_sizes, int n_in,
                              void* d_out, int out_size, void* d_ws, size_t ws_size,
                              hipStream_t stream)
{
    const float* coords = (const float*)d_in[0];
    const float* fw0 = (const float*)d_in[1];
    const float* fb0 = (const float*)d_in[2];
    const float* fw1 = (const float*)d_in[3];
    const float* fb1 = (const float*)d_in[4];
    const float* aw0 = (const float*)d_in[5];
    const float* ab0 = (const float*)d_in[6];
    const float* aw1 = (const float*)d_in[7];
    const float* ab1 = (const float*)d_in[8];
    const float* aw2 = (const float*)d_in[9];
    const float* ab2 = (const float*)d_in[10];
    const float* uw0 = (const float*)d_in[11];
    const float* ub0 = (const float*)d_in[12];
    const float* uw1 = (const float*)d_in[13];
    const float* ub1 = (const float*)d_in[14];
    float* out = (float*)d_out;

    // workspace layout
    char* ws = (char*)d_ws;
    __bf16* A    = (__bf16*)(ws);                            // 4 MB
    __bf16* h_t  = (__bf16*)(ws + (4u << 20));               // 1 MB
    __bf16* h_bf = (__bf16*)(ws + (5u << 20));               // 1 MB
    __bf16* w0t  = (__bf16*)(ws + (6u << 20));               // 128 KB
    __bf16* w1t  = (__bf16*)(ws + (6u << 20) + (128u << 10));// 64 KB

    k_mega<<<2436, 256, 0, stream>>>(coords, fw0, fb0, fw1, fb1,
                                     aw0, ab0, aw1, ab1, aw2, ab2, uw0, uw1,
                                     h_bf, h_t, w0t, w1t, A, out, out_size);
    k_aggupd<<<256, 1024, 0, stream>>>(A, h_t, h_bf, coords, uw0, ub0,
                                       w0t, w1t, ub1, out);
}

// Round 5
// 122.386 us; speedup vs baseline: 1.0630x; 1.0570x over previous
//
#include <hip/hip_runtime.h>
#include <hip/hip_bf16.h>

#define B_ 8
#define N_ 512

typedef __attribute__((ext_vector_type(8))) __bf16 bf16x8;
typedef __attribute__((ext_vector_type(8))) _Float16 f16x8;
typedef __attribute__((ext_vector_type(4))) _Float16 f16x4;
typedef __attribute__((ext_vector_type(2))) _Float16 h2;
typedef __attribute__((ext_vector_type(4))) float f32x4;
typedef __attribute__((ext_vector_type(4))) unsigned int u32x4;
typedef __attribute__((ext_vector_type(2))) unsigned int u32x2;

// pack two fp32 into bf16x2 by truncation: 1 v_perm_b32
__device__ __forceinline__ unsigned pk_bf16(float hi, float lo) {
    return __builtin_amdgcn_perm(__builtin_bit_cast(unsigned, hi),
                                 __builtin_bit_cast(unsigned, lo), 0x07060302u);
}

__device__ __forceinline__ h2 pkrtz(float a, float b) {
    return __builtin_bit_cast(h2, __builtin_amdgcn_cvt_pkrtz(a, b));
}
__device__ __forceinline__ unsigned pkrtz_u(float a, float b) {
    return __builtin_bit_cast(unsigned, __builtin_amdgcn_cvt_pkrtz(a, b));
}
// relu (pk_max_f16 vs 0) on a packed pair, returned as dword
__device__ __forceinline__ unsigned relu2_u(h2 v) {
    const h2 z2 = {(_Float16)0.0f, (_Float16)0.0f};
    return __builtin_bit_cast(unsigned, __builtin_elementwise_max(v, z2));
}

// ---------------- prep kernel: node MLP | w0t/w1t transpose | zero out ------
// [0,1024)     node MLP, 4 rows/block
// [1024,1280)  w0t transpose (coalesced reads)
// [1280,1408)  w1t transpose
// [1408,1412)  zero d_out
__global__ __launch_bounds__(256) void k_prep(
    const float* __restrict__ coords,
    const float* __restrict__ fw0, const float* __restrict__ fb0,
    const float* __restrict__ fw1, const float* __restrict__ fb1,
    const float* __restrict__ uw0, const float* __restrict__ uw1,
    __bf16* __restrict__ h_bf, __bf16* __restrict__ h_t,
    __bf16* __restrict__ w0t, __bf16* __restrict__ w1t,
    float* __restrict__ out, int out_size)
{
    const int blk = blockIdx.x;
    const int t = threadIdx.x;

    if (blk < 1024) {
        // ================= node MLP: 4 rows/block =================
        const int row0 = blk << 2;
        const int b = row0 >> 9;
        const int n0 = row0 & 511;
        __shared__ float cds4[4][4];
        __shared__ float hid4[4][64];
        if (t < 12) {
            int r = t / 3, d = t - 3 * r;
            cds4[r][d] = coords[(size_t)row0 * 3 + t];
        }
        __syncthreads();
        {
            int r = t >> 6, ch = t & 63;
            float v = fb0[ch];
            v += cds4[r][0] * fw0[0 * 64 + ch];
            v += cds4[r][1] * fw0[1 * 64 + ch];
            v += cds4[r][2] * fw0[2 * 64 + ch];
            hid4[r][ch] = fmaxf(v, 0.0f);
        }
        __syncthreads();
        {
            int ch = t & 127;
            int rp = (t >> 7) << 1;          // rows rp, rp+1
            float hv0 = fb1[ch], hv1 = hv0;
#pragma unroll 4
            for (int k = 0; k < 64; ++k) {
                float w = fw1[k * 128 + ch];
                hv0 += hid4[rp][k] * w;
                hv1 += hid4[rp + 1][k] * w;
            }
            hv0 = fmaxf(hv0, 0.0f);
            hv1 = fmaxf(hv1, 0.0f);
            h_bf[((size_t)(row0 + rp) << 7) + ch] = (__bf16)hv0;
            h_bf[((size_t)(row0 + rp + 1) << 7) + ch] = (__bf16)hv1;
            *(unsigned*)(h_t + (size_t)(b * 128 + ch) * 512 + n0 + rp) =
                pk_bf16(hv1, hv0);
        }
    } else if (blk < 1280) {
        // ---- w0t[c][k] = uw0[perm(k)][c]; coalesced read ----
        int k = blk - 1024;
        int c = t;
        int src = (k < 128) ? k : (k + 3);
        w0t[(size_t)c * 256 + k] = (__bf16)uw0[(size_t)src * 256 + c];
    } else if (blk < 1408) {
        // ---- w1t[c][k] = uw1[k][c]; coalesced read ----
        int id = (blk - 1280) * 256 + t;
        int c = id & 127, k = id >> 7;
        w1t[(size_t)c * 256 + k] = (__bf16)uw1[(size_t)k * 128 + c];
    } else {
        int i = (blk - 1408) * 256 + t;
        if (i < out_size) out[i] = 0.0f;
    }
}

// ---------------- fused kernel: adjacency MLP -> LDS A-tile -> V=A@h -> MLP -
// 256 blocks x 1024 thr (16 waves). Block owns 16 global rows (one 16-row
// output tile). Phase 1: each wave computes ONE i-row x 512 j of the
// adjacency MLP (x16 L0 / x32 L1 / x32-dense L2, all verified layouts) into
// LDS As[16][520] (pad breaks b128 read conflicts). Phase 2: V = As @ h_t
// (MFMA, K-split x2). Phase 3: update MLP + maxpool (unchanged).
// Removes the 4MB A global round-trip and the grid-wide adjacency->aggregate
// serialization of the old two-kernel structure.
#define AP 520
__global__ __launch_bounds__(1024) void k_fused(
    const float* __restrict__ coords,
    const float* __restrict__ aw0, const float* __restrict__ ab0,
    const float* __restrict__ aw1, const float* __restrict__ ab1,
    const float* __restrict__ aw2, const float* __restrict__ ab2,
    const __bf16* __restrict__ h_t, const __bf16* __restrict__ h_bf,
    const float* __restrict__ uw0, const float* __restrict__ ub0,
    const __bf16* __restrict__ w0t, const __bf16* __restrict__ w1t,
    const float* __restrict__ ub1,
    float* __restrict__ out)
{
    const int t = threadIdx.x;
    const int w = t >> 6;            // wave 0..15
    const int l = t & 63;
    const int q = l >> 4;
    const int m = l & 15;
    const int row0 = blockIdx.x << 4;   // 16 GLOBAL rows, same b
    const int b = row0 >> 9;

    __shared__ __align__(16) _Float16 s_aw1p[4096];      // 8 KB
    __shared__ __align__(16) float s_w[576];             // aw0|ab0|aw2|ab1
    __shared__ __align__(8) unsigned s_cj[512][2];       // 4 KB
    __shared__ __align__(16) __bf16 As[16][AP];          // 16.6 KB A-tile
    __shared__ __align__(16) __bf16 act[16][264];        // [row][k], k=[h|V]
    __shared__ __align__(16) __bf16 u1[16][264];
    __shared__ float vp[2][16][128];                     // 16 KB
    __shared__ float cds[16][4];

    // ================= staging (all 1024 threads) =================
    {
        // aw1: coalesced read (thread owns 4 consecutive floats), f16
        // scatter-store into fragment layout.
        f32x4 wv = *(const f32x4*)(aw1 + t * 4);
        const int R = t >> 4;
        const int C4 = (t & 15) << 2;
        const int s = R >> 5, qq = (R >> 3) & 3, j = R & 7;
        const int ct = C4 >> 4, mm0 = C4 & 15;
        const int base = s * 2048 + ct * 512 + qq * 128 + mm0 * 8 + j;
#pragma unroll
        for (int e = 0; e < 4; ++e)
            s_aw1p[base + e * 8] = (_Float16)wv[e];

        // aw0(384) | ab0(64) | aw2(64) | ab1(64) -> s_w[0..576)
        if (t < 144) {
            const int o = t * 4;
            f32x4 v;
            if (o < 384)      v = *(const f32x4*)(aw0 + o);
            else if (o < 448) v = *(const f32x4*)(ab0 + (o - 384));
            else if (o < 512) v = *(const f32x4*)(aw2 + (o - 448));
            else              v = *(const f32x4*)(ab1 + (o - 512));
            *(f32x4*)&s_w[o] = v;
        }

        // cj for all 512 j of batch b, packed f16 {c0,c1,c2,1}
        if (t < 512) {
            const float* cj = coords + ((size_t)b * N_ + t) * 3;
            s_cj[t][0] = pkrtz_u(cj[0], cj[1]);
            s_cj[t][1] = pkrtz_u(cj[2], 1.0f);
        }

        // stage h part of act: 1024 thr x 4B covers 16x128 bf16
        unsigned hv = *(const unsigned*)(h_bf + ((size_t)row0 << 7) + t * 2);
        *(unsigned*)&act[(t * 2) >> 7][(t * 2) & 127] = hv;

        if (t < 48) {
            int r = t / 3, d = t - 3 * r;
            cds[r][d] = coords[(size_t)row0 * 3 + t];
        }
    }
    __syncthreads();

    // ================= phase 1: adjacency MLP, wave w -> row w ==========
    {
        const float* cp = coords + (size_t)(row0 + w) * 3;
        const float ci0 = cp[0], ci1 = cp[1], ci2 = cp[2];

        // layer-0 A-fragments (x16 shape, k=0..3 live), row-permuted so
        // D == layer-1 B layout: t4 row m -> ch = (m>>2)*8+(m&3)+{0,4,32,36}
        f16x4 a0f[4];
        {
            const int chb = ((m >> 2) << 3) + (m & 3);
            const int offs[4] = {0, 4, 32, 36};
#pragma unroll
            for (int t4 = 0; t4 < 4; ++t4) {
                const int ch = chb + offs[t4];
                float o = s_w[384 + ch] + ci0 * s_w[ch] + ci1 * s_w[64 + ch]
                                        + ci2 * s_w[128 + ch];
                u32x2 fr;
                fr[0] = (q == 0) ? pkrtz_u(s_w[192 + ch], s_w[256 + ch]) : 0u;
                fr[1] = (q == 0) ? pkrtz_u(s_w[320 + ch], o) : 0u;
                a0f[t4] = __builtin_bit_cast(f16x4, fr);
            }
        }

        // layer-2 reduction A-fragments, x32 dense (K=32 full)
        f16x8 ewf[2];
#pragma unroll
        for (int g = 0; g < 2; ++g) {
            const float* e0 = &s_w[448 + g * 32 + (q << 2)];
            const float* e1 = e0 + 16;
            u32x4 fr;
            fr[0] = pkrtz_u(e0[0], e0[1]);
            fr[1] = pkrtz_u(e0[2], e0[3]);
            fr[2] = pkrtz_u(e1[0], e1[1]);
            fr[3] = pkrtz_u(e1[2], e1[3]);
            ewf[g] = __builtin_bit_cast(f16x8, fr);
        }

        f16x8 bfr[2][4];
#pragma unroll
        for (int s = 0; s < 2; ++s)
#pragma unroll
            for (int ct = 0; ct < 4; ++ct)
                bfr[s][ct] = *(const f16x8*)&s_aw1p[s * 2048 + ct * 512 + q * 128 + m * 8];

        f32x4 ab1q[4];
#pragma unroll
        for (int ct = 0; ct < 4; ++ct)
            ab1q[ct] = *(const f32x4*)&s_w[512 + ct * 16 + (q << 2)];

        const float ab2s = ab2[0];
        const f32x4 pr0 = {ab2s, ab2s, ab2s, ab2s};
        const f32x4 zf = {0.f, 0.f, 0.f, 0.f};

#pragma unroll 1
        for (int tt = 0; tt < 32; ++tt) {
            f16x4 bj = __builtin_bit_cast(f16x4, *(const u32x2*)s_cj[(tt << 4) + m]);

            // layer 0: 4 row-permuted x16 MFMAs (k=0..3 live)
            f32x4 d0 = __builtin_amdgcn_mfma_f32_16x16x16f16(a0f[0], bj, zf, 0, 0, 0);
            f32x4 d1 = __builtin_amdgcn_mfma_f32_16x16x16f16(a0f[1], bj, zf, 0, 0, 0);
            f32x4 d2 = __builtin_amdgcn_mfma_f32_16x16x16f16(a0f[2], bj, zf, 0, 0, 0);
            f32x4 d3 = __builtin_amdgcn_mfma_f32_16x16x16f16(a0f[3], bj, zf, 0, 0, 0);

            // relu + pack straight into layer-1 B-fragments
            u32x4 pa, pb;
            pa[0] = relu2_u(pkrtz(d0[0], d0[1]));
            pa[1] = relu2_u(pkrtz(d0[2], d0[3]));
            pa[2] = relu2_u(pkrtz(d1[0], d1[1]));
            pa[3] = relu2_u(pkrtz(d1[2], d1[3]));
            pb[0] = relu2_u(pkrtz(d2[0], d2[1]));
            pb[1] = relu2_u(pkrtz(d2[2], d2[3]));
            pb[2] = relu2_u(pkrtz(d3[0], d3[1]));
            pb[3] = relu2_u(pkrtz(d3[2], d3[3]));
            f16x8 a0 = __builtin_bit_cast(f16x8, pa);
            f16x8 a1 = __builtin_bit_cast(f16x8, pb);

            // layer 1 transposed MFMA (f16); ab1 folded into C
            f32x4 c0v = __builtin_amdgcn_mfma_f32_16x16x32_f16(bfr[0][0], a0, ab1q[0], 0, 0, 0);
            c0v = __builtin_amdgcn_mfma_f32_16x16x32_f16(bfr[1][0], a1, c0v, 0, 0, 0);
            f32x4 c1v = __builtin_amdgcn_mfma_f32_16x16x32_f16(bfr[0][1], a0, ab1q[1], 0, 0, 0);
            c1v = __builtin_amdgcn_mfma_f32_16x16x32_f16(bfr[1][1], a1, c1v, 0, 0, 0);
            f32x4 c2v = __builtin_amdgcn_mfma_f32_16x16x32_f16(bfr[0][2], a0, ab1q[2], 0, 0, 0);
            c2v = __builtin_amdgcn_mfma_f32_16x16x32_f16(bfr[1][2], a1, c2v, 0, 0, 0);
            f32x4 c3v = __builtin_amdgcn_mfma_f32_16x16x32_f16(bfr[0][3], a0, ab1q[3], 0, 0, 0);
            c3v = __builtin_amdgcn_mfma_f32_16x16x32_f16(bfr[1][3], a1, c3v, 0, 0, 0);

            // layer 2: relu + pack, K=32 repack -> 2 dense x32 MFMAs
            u32x4 B0, B1;
            B0[0] = relu2_u(pkrtz(c0v[0], c0v[1]));
            B0[1] = relu2_u(pkrtz(c0v[2], c0v[3]));
            B0[2] = relu2_u(pkrtz(c1v[0], c1v[1]));
            B0[3] = relu2_u(pkrtz(c1v[2], c1v[3]));
            B1[0] = relu2_u(pkrtz(c2v[0], c2v[1]));
            B1[1] = relu2_u(pkrtz(c2v[2], c2v[3]));
            B1[2] = relu2_u(pkrtz(c3v[0], c3v[1]));
            B1[3] = relu2_u(pkrtz(c3v[2], c3v[3]));

            f32x4 pr = __builtin_amdgcn_mfma_f32_16x16x32_f16(
                ewf[0], __builtin_bit_cast(f16x8, B0), pr0, 0, 0, 0);
            pr = __builtin_amdgcn_mfma_f32_16x16x32_f16(
                ewf[1], __builtin_bit_cast(f16x8, B1), pr, 0, 0, 0);

            if (l < 16) As[w][(tt << 4) + l] = (__bf16)fmaxf(pr[0], 0.0f);
        }
    }
    __syncthreads();

    // ================= phase 2: V = As @ h_t (K-split x2) =================
    const int gw = w & 7;            // n-tile
    const int ks = w >> 3;           // K-half
    {
        const __bf16* hp = h_t + ((size_t)b << 16) + (size_t)(gw * 16 + m) * 512
                           + ks * 256 + q * 8;
        const __bf16* Ar = &As[m][ks * 256 + q * 8];
        f32x4 acc = {0.f, 0.f, 0.f, 0.f};
#pragma unroll 4
        for (int kt = 0; kt < 8; ++kt) {
            bf16x8 av = *(const bf16x8*)(Ar + kt * 32);
            bf16x8 bv = *(const bf16x8*)(hp + kt * 32);
            acc = __builtin_amdgcn_mfma_f32_16x16x32_bf16(av, bv, acc, 0, 0, 0);
        }
#pragma unroll
        for (int r = 0; r < 4; ++r)
            vp[ks][q * 4 + r][gw * 16 + m] = acc[r];
    }
    __syncthreads();

    // combine K-halves -> act V part (1024 thr x 2 values)
#pragma unroll
    for (int it = 0; it < 2; ++it) {
        int idx = t + it * 1024;
        int row = idx >> 7, ch = idx & 127;
        act[row][128 + ch] = (__bf16)(vp[0][row][ch] + vp[1][row][ch]);
    }
    __syncthreads();

    // ================= phase 3: update MLP + maxpool =================
    bf16x8 af[8];
#pragma unroll
    for (int ch = 0; ch < 8; ++ch)
        af[ch] = *(const bf16x8*)&act[m][q * 8 + 32 * ch];
    {
        const int c = w * 16 + m;
        const float wx = uw0[128 * 256 + c];
        const float wy = uw0[129 * 256 + c];
        const float wz = uw0[130 * 256 + c];
        const float bias = ub0[c];
        f32x4 a1c;
#pragma unroll
        for (int r = 0; r < 4; ++r)
            a1c[r] = bias + cds[q * 4 + r][0] * wx + cds[q * 4 + r][1] * wy
                          + cds[q * 4 + r][2] * wz;
        const __bf16* wp = w0t + (size_t)c * 256 + q * 8;
#pragma unroll
        for (int ch = 0; ch < 8; ++ch) {
            bf16x8 bfr = *(const bf16x8*)(wp + 32 * ch);
            a1c = __builtin_amdgcn_mfma_f32_16x16x32_bf16(af[ch], bfr, a1c, 0, 0, 0);
        }
#pragma unroll
        for (int r = 0; r < 4; ++r)
            u1[q * 4 + r][c] = (__bf16)fmaxf(a1c[r], 0.0f);
    }
    __syncthreads();

    if (w < 8) {
        bf16x8 af2[8];
#pragma unroll
        for (int ch = 0; ch < 8; ++ch)
            af2[ch] = *(const bf16x8*)&u1[m][q * 8 + 32 * ch];
        const int c = w * 16 + m;
        float bias = ub1[c];
        f32x4 a2c = {bias, bias, bias, bias};
        const __bf16* wp = w1t + (size_t)c * 256 + q * 8;
#pragma unroll
        for (int ch = 0; ch < 8; ++ch) {
            bf16x8 bfr = *(const bf16x8*)(wp + 32 * ch);
            a2c = __builtin_amdgcn_mfma_f32_16x16x32_bf16(af2[ch], bfr, a2c, 0, 0, 0);
        }
        float mx = fmaxf(fmaxf(a2c[0], a2c[1]), fmaxf(a2c[2], a2c[3]));
        mx = fmaxf(mx, 0.0f);
        mx = fmaxf(mx, __shfl_xor(mx, 16, 64));
        mx = fmaxf(mx, __shfl_xor(mx, 32, 64));
        if (l < 16)
            atomicMax((int*)(out + ((size_t)b << 7) + c), __float_as_int(mx));
    }
}

extern "C" void kernel_launch(void* const* d_in, const int* in_sizes, int n_in,
                              void* d_out, int out_size, void* d_ws, size_t ws_size,
                              hipStream_t stream)
{
    const float* coords = (const float*)d_in[0];
    const float* fw0 = (const float*)d_in[1];
    const float* fb0 = (const float*)d_in[2];
    const float* fw1 = (const float*)d_in[3];
    const float* fb1 = (const float*)d_in[4];
    const float* aw0 = (const float*)d_in[5];
    const float* ab0 = (const float*)d_in[6];
    const float* aw1 = (const float*)d_in[7];
    const float* ab1 = (const float*)d_in[8];
    const float* aw2 = (const float*)d_in[9];
    const float* ab2 = (const float*)d_in[10];
    const float* uw0 = (const float*)d_in[11];
    const float* ub0 = (const float*)d_in[12];
    const float* uw1 = (const float*)d_in[13];
    const float* ub1 = (const float*)d_in[14];
    float* out = (float*)d_out;

    // workspace layout
    char* ws = (char*)d_ws;
    __bf16* h_t  = (__bf16*)(ws);                            // 1 MB
    __bf16* h_bf = (__bf16*)(ws + (1u << 20));               // 1 MB
    __bf16* w0t  = (__bf16*)(ws + (2u << 20));               // 128 KB
    __bf16* w1t  = (__bf16*)(ws + (2u << 20) + (128u << 10));// 64 KB

    k_prep<<<1412, 256, 0, stream>>>(coords, fw0, fb0, fw1, fb1, uw0, uw1,
                                     h_bf, h_t, w0t, w1t, out, out_size);
    k_fused<<<256, 1024, 0, stream>>>(coords, aw0, ab0, aw1, ab1, aw2, ab2,
                                      h_t, h_bf, uw0, ub0, w0t, w1t, ub1, out);
}